// Round 11
// baseline (26.130 us; speedup 1.0000x reference)
//
#include <hip/hip_runtime.h>

// ---------------- problem constants ----------------
#define B_    8192
#define K_    784      // IN_DIM
#define KP2   832      // Sq row stride (13*64 bytes)
#define NKT   7        // K tiles of 128 (tile 6: only first half is real)
#define RP    1024     // unique w1 rows = HIDDEN/CF
#define HID   4096
#define OD    10
#define TS2   10240    // OUT_DIM*HIDDEN/CF

#define NB_XQ 1792     // 8192*56/256  (x -> i8, fragment-ordered)
#define NB_SQ 208      // 1024*52/256  (tile1 -> +/-1 i8, row layout)
#define NB_F  64       // 16*1024/256  (Vfrag bf16)
#define NB_Z  80       // 80*256*4 = 81920 floats of out zeroing

typedef __attribute__((ext_vector_type(8))) short  bf16x8;
typedef __attribute__((ext_vector_type(4))) int    i32x4;
typedef __attribute__((ext_vector_type(4))) float  f32x4;

__device__ __forceinline__ unsigned short f2bf(float f) {
    unsigned u = __builtin_bit_cast(unsigned, f);
    u += 0x7fffu + ((u >> 16) & 1u);          // RNE
    return (unsigned short)(u >> 16);
}
__device__ __forceinline__ int qz32(float v) {  // q = rint(clamp(32x))
    v = fminf(fmaxf(v * 32.f, -127.f), 127.f);
    return (int)__builtin_rintf(v);
}

// ================= merged prep kernel =====================================
// blocks [0, NB_XQ): x -> i8 in MFMA A-FRAGMENT order. Frag id
//   fid = ((p*8 + mi)*7 + t)*2 + h  (p=row/128, mi=frag-in-panel, t=K-tile,
//   h=half). Lane l holds row p*128+mi*16+(l&15), k = t*128+h*64+(l>>4)*16
//   .. +15. Linear write: Xqf[id*16..+15], id = fid*64 + lane.
// blocks [.., +NB_SQ): tile1 -> +/-1 i8, row layout [row][kb][s][e], 832B
//   rows, s ^ xi(row) slot swizzle, xi=(row>>1)&3, zero beyond col 784.
// blocks [.., +NB_F) : Vfrag (bf16, MFMA B-fragment order, o padded to 16)
// blocks [.., +NB_Z) : zero out[]
__global__ __launch_bounds__(256) void prep(
    const float* __restrict__ x, const int* __restrict__ t1,
    const int* __restrict__ t2, const float* __restrict__ a1,
    const float* __restrict__ a2,
    signed char* __restrict__ Xqf, signed char* __restrict__ Sq,
    unsigned short* __restrict__ Vfrag, float* __restrict__ out)
{
    const int b = blockIdx.x;
    if (b < NB_XQ) {
        const int id   = b * 256 + threadIdx.x;     // < 458752
        const int lane = id & 63;
        const int fid  = id >> 6;                   // < 7168
        const int h    = fid & 1;
        const int q    = fid >> 1;                  // < 3584
        const int t    = q % 7;
        const int pm   = q / 7;                     // < 512
        const int row  = (pm >> 3) * 128 + (pm & 7) * 16 + (lane & 15);
        const int k0   = t * 128 + h * 64 + ((lane >> 4) << 4);
        i32x4 w = {0, 0, 0, 0};
        if (k0 < K_) {                              // 784%16==0: all-or-none
            const float* xp = x + (size_t)row * K_ + k0;
            #pragma unroll
            for (int g = 0; g < 4; ++g) {
                f32x4 a = *(const f32x4*)(xp + g * 4);
                const int q0 = qz32(a.x), q1 = qz32(a.y);
                const int q2 = qz32(a.z), q3 = qz32(a.w);
                w[g] = (q0 & 255) | ((q1 & 255) << 8) |
                       ((q2 & 255) << 16) | ((q3 & 255) << 24);
            }
        }
        *(i32x4*)(Xqf + (size_t)id * 16) = w;
    } else if (b < NB_XQ + NB_SQ) {
        const int id  = (b - NB_XQ) * 256 + threadIdx.x;   // < 1024*52
        const int row = id / 52;
        const int rem = id - row * 52;
        const int kb  = rem >> 2;                   // 0..12
        const int s   = rem & 3;
        const int xi  = (row >> 1) & 3;
        const int k0  = kb * 64 + ((s ^ xi) << 4);
        i32x4 w = {0, 0, 0, 0};
        if (k0 < K_) {
            const int* tp = t1 + (size_t)row * K_ + k0;
            #pragma unroll
            for (int g = 0; g < 4; ++g) {
                int wg = 0;
                #pragma unroll
                for (int j = 0; j < 4; ++j)
                    wg |= (tp[g * 4 + j] ? 0x01 : 0xFF) << (8 * j);
                w[g] = wg;
            }
        }
        *(i32x4*)(Sq + (size_t)row * KP2 + kb * 64 + s * 16) = w;
    } else if (b < NB_XQ + NB_SQ + NB_F) {
        const int id = (b - NB_XQ - NB_SQ) * 256 + threadIdx.x;   // < 16384
        const int o = id >> 10;           // 0..15 (10..15 are zero pad)
        const int r = id & 1023;
        float v = 0.f;
        if (o < OD) {
            #pragma unroll
            for (int c = 0; c < 4; ++c) {
                const int idx = o * HID + c * RP + r;
                const int ch  = idx / TS2;
                const float w2v = a2[ch] * (float)(2 * t2[idx - ch * TS2] - 1);
                v = fmaf(a1[c], w2v, v);
            }
        }
        Vfrag[(r >> 5) * 512 + (o + 16 * ((r >> 3) & 3)) * 8 + (r & 7)] = f2bf(v);
    } else {
        const int id = (b - NB_XQ - NB_SQ - NB_F) * 256 + threadIdx.x;
        ((f32x4*)out)[id] = (f32x4){0.f, 0.f, 0.f, 0.f};
    }
}

// ================= GEMM1 (i8) + fused layer 2 =============================
// 128x128 tile, BK=128, 7 steps, r10 pipeline (counted vmcnt + raw barriers,
// 1-deep prefetch) BUT: A operand global->REGISTER (fragment-ordered Xqf,
// double-buffered aA[2][8]); only B goes through LDS (2 x 16KB buffers).
// LDS traffic -40%. Tile 6's pad half skipped (exact zeros). 4 waves 2x2,
// 512 blocks XCD-chunked = 2/CU. Exact i32 accumulate; dequant /32.
// Epilogue: relu->bf16->Hlds overlay, bf16 mini-GEMM vs Vfrag, atomicAdd.
__global__ __launch_bounds__(256, 2) void gemm1(const signed char* __restrict__ Xqf,
                                                const signed char* __restrict__ Sq,
                                                const unsigned short* __restrict__ Vfrag,
                                                float* __restrict__ out) {
    __shared__ unsigned char SH[32768];   // 2 B-buffers x {h0 8K | h1 8K}; then Hlds

    const int tid  = threadIdx.x;
    const int lane = tid & 63;
    const int wid  = tid >> 6;

    // bijective XCD-chunked swizzle: XCD k owns bm-tiles [8k, 8k+8) x all bn
    const int swz = (blockIdx.x & 7) * 64 + (blockIdx.x >> 3);
    const int bm  = (swz >> 3) * 128;
    const int bn  = (swz & 7) * 128;

    const int wr = (wid >> 1) * 64;
    const int wc = (wid & 1) * 64;

    // B staging lane constants (16 rows x 64B per 1KB gload chunk)
    const int srow = lane >> 2;                  // 0..15 row within chunk
    const int sslt = (lane & 3) << 4;            // byte slot offset in 64B row

    // B fragment-read lane constants
    const int kg   = lane >> 4;                  // 0..3 k-group
    const int xr   = ((lane & 15) >> 1) & 3;     // xi of frag row
    const int fsl  = (kg ^ xr) << 4;             // physical slot bytes
    const int frow = lane & 15;

    // A fragment base: frag (mi_g, t, h) at (( (bm/128)*8 + mi_g)*14 + t*2 + h)*1024
    const int wrMi = (wid >> 1) * 4;             // this wave's first A frag
    const signed char* ap = Xqf + (size_t)(bm >> 7) * 114688
                                + (size_t)wrMi * 14336 + lane * 16;

    i32x4 acc[4][4] = {};
    i32x4 aA[2][8];                              // [buf][h*4+mi] (static idx)

#define STAGE_B(T, NXT, NH)                                                     \
    do {                                                                        \
        _Pragma("unroll")                                                       \
        for (int i = 0; i < 2; ++i) {                                           \
            const int row = wid * 32 + i * 16 + srow;                           \
            const signed char* gb = Sq + (size_t)(bn + row) * KP2 + (T) * 128 + sslt; \
            __builtin_amdgcn_global_load_lds(                                   \
                (const __attribute__((address_space(1))) void*)gb,              \
                (__attribute__((address_space(3))) void*)                       \
                    (&SH[(NXT) * 16384 + wid * 2048 + i * 1024 + lane * 16]),   \
                16, 0, 0);                                                      \
            if ((NH) == 2)                                                      \
                __builtin_amdgcn_global_load_lds(                               \
                    (const __attribute__((address_space(1))) void*)(gb + 64),   \
                    (__attribute__((address_space(3))) void*)                   \
                        (&SH[(NXT) * 16384 + 8192 + wid * 2048 + i * 1024 + lane * 16]), \
                    16, 0, 0);                                                  \
        }                                                                       \
    } while (0)

#define LOAD_A(T, NXT, NH)                                                      \
    do {                                                                        \
        _Pragma("unroll")                                                       \
        for (int h = 0; h < (NH); ++h)                                          \
            _Pragma("unroll")                                                   \
            for (int mi = 0; mi < 4; ++mi)                                      \
                aA[NXT][h * 4 + mi] =                                           \
                    *(const i32x4*)(ap + mi * 14336 + (T) * 2048 + h * 1024);   \
    } while (0)

    // prologue: tile 0 in flight (B 4 gload_lds + A 8 reg loads per wave)
    STAGE_B(0, 0, 2);
    LOAD_A(0, 0, 2);

    #pragma unroll
    for (int t = 0; t < NKT; ++t) {
        const int cur = t & 1;
        if (t < 5) {
            STAGE_B(t + 1, cur ^ 1, 2);          // +4 gload_lds
            LOAD_A(t + 1, cur ^ 1, 2);           // +8 reg loads
            asm volatile("s_waitcnt vmcnt(12)" ::: "memory");  // tile t done
        } else if (t == 5) {
            STAGE_B(6, cur ^ 1, 1);              // +2 (pad half skipped)
            LOAD_A(6, cur ^ 1, 1);               // +4
            asm volatile("s_waitcnt vmcnt(6)" ::: "memory");   // tile 5 done
        } else {
            asm volatile("s_waitcnt vmcnt(0)" ::: "memory");   // tile 6 done
        }
        __builtin_amdgcn_s_barrier();            // publish B (no vmcnt drain)
        __builtin_amdgcn_sched_barrier(0);

        const int halves = (t == NKT - 1) ? 1 : 2;
        #pragma unroll
        for (int h = 0; h < 2; ++h) {
            if (h < halves) {
                i32x4 bfr[4];
                #pragma unroll
                for (int ni = 0; ni < 4; ++ni)
                    bfr[ni] = *(const i32x4*)&SH[cur * 16384 + h * 8192
                                                 + (wc + ni * 16 + frow) * 64 + fsl];
                #pragma unroll
                for (int mi = 0; mi < 4; ++mi)
                    #pragma unroll
                    for (int ni = 0; ni < 4; ++ni)
                        acc[mi][ni] = __builtin_amdgcn_mfma_i32_16x16x64_i8(
                            aA[cur][h * 4 + mi], bfr[ni], acc[mi][ni], 0, 0, 0);
            }
        }
        __builtin_amdgcn_sched_barrier(0);
        __builtin_amdgcn_s_barrier();            // all done reading cur B buf
    }
#undef STAGE_B
#undef LOAD_A

    // ---- fused epilogue ----------------------------------------------------
    // 1) dequant + relu -> bf16 -> Hlds[128][128] (col-slot XOR swizzle)
    unsigned short* Hlds = (unsigned short*)SH;   // 128*128 ushorts = 32 KB
    __syncthreads();                              // all SH reads complete
    #pragma unroll
    for (int mi = 0; mi < 4; ++mi) {
        #pragma unroll
        for (int ni = 0; ni < 4; ++ni) {
            const int col = wc + ni * 16 + (lane & 15);
            #pragma unroll
            for (int r = 0; r < 4; ++r) {
                const int row = wr + mi * 16 + (lane >> 4) * 4 + r;
                const float hv = (float)acc[mi][ni][r] * 0.03125f;   // /32 exact
                Hlds[row * 128 + ((((col >> 3) ^ (row & 7)) << 3) | (col & 7))]
                    = f2bf(fmaxf(hv, 0.f));
            }
        }
    }
    __syncthreads();

    // 2) P[128,16] = H_tile @ V_slice^T via 8 MFMAs; wave handles 2 m-frags
    const int kb0 = bn >> 5;                   // first 32-wide k-frag of this bn
    bf16x8 vb[4];
    #pragma unroll
    for (int kk = 0; kk < 4; ++kk)
        vb[kk] = *(const bf16x8*)&Vfrag[(kb0 + kk) * 512 + lane * 8];

    #pragma unroll
    for (int mf = 0; mf < 2; ++mf) {
        const int mloc = (wid * 2 + mf) * 16;  // m-frag base row (0..112)
        const int mrow = mloc + (lane & 15);
        f32x4 pac = {};
        #pragma unroll
        for (int kk = 0; kk < 4; ++kk) {
            const int slot = kk * 4 + (lane >> 4);
            bf16x8 ha = *(const bf16x8*)&Hlds[mrow * 128 + ((slot ^ (mrow & 7)) << 3)];
            pac = __builtin_amdgcn_mfma_f32_16x16x32_bf16(ha, vb[kk], pac, 0, 0, 0);
        }
        const int o = lane & 15;
        if (o < OD) {
            #pragma unroll
            for (int r = 0; r < 4; ++r) {
                const int rowg = bm + mloc + (lane >> 4) * 4 + r;
                atomicAdd(&out[(size_t)rowg * OD + o], pac[r]);
            }
        }
    }
}

// ================= fallback (round-1 f32 SIMT fused kernel) ================
#define BM 128
#define BN 128
#define BK 16
__global__ __launch_bounds__(256, 2) void fused_tilednn(
    const float* __restrict__ x, const int* __restrict__ tile1,
    const float* __restrict__ alphas1, const int* __restrict__ tile2,
    const float* __restrict__ alphas2, float* __restrict__ out)
{
    __shared__ float XsF[BK][BM];
    __shared__ float SsF[BK][BN];
    __shared__ float Vl[OD][BN];
    const int t = threadIdx.x, tx = t & 15, ty = t >> 4;
    const int bm = blockIdx.x * BM, bn = blockIdx.y * BN;
    for (int e = t; e < OD * BN; e += 256) {
        const int o = e / BN, rl = e - o * BN, rr = bn + rl;
        float v = 0.f;
        #pragma unroll
        for (int c = 0; c < 4; ++c) {
            const int idx = o * HID + c * RP + rr;
            const int ch = idx / TS2;
            v = fmaf(alphas1[c], alphas2[ch] * (float)(2 * tile2[idx - ch * TS2] - 1), v);
        }
        Vl[o][rl] = v;
    }
    float acc[8][8];
    #pragma unroll
    for (int i = 0; i < 8; ++i)
        #pragma unroll
        for (int j = 0; j < 8; ++j) acc[i][j] = 0.f;
    const int lr = t >> 1, lk = (t & 1) << 3;
    const float* xrow = x + (size_t)(bm + lr) * K_;
    const int* srow = tile1 + (size_t)(bn + lr) * K_;
    for (int k0 = 0; k0 < K_; k0 += BK) {
        __syncthreads();
        const float4 xa = *(const float4*)(xrow + k0 + lk);
        const float4 xb = *(const float4*)(xrow + k0 + lk + 4);
        const int4 sa = *(const int4*)(srow + k0 + lk);
        const int4 sb = *(const int4*)(srow + k0 + lk + 4);
        XsF[lk+0][lr]=xa.x; XsF[lk+1][lr]=xa.y; XsF[lk+2][lr]=xa.z; XsF[lk+3][lr]=xa.w;
        XsF[lk+4][lr]=xb.x; XsF[lk+5][lr]=xb.y; XsF[lk+6][lr]=xb.z; XsF[lk+7][lr]=xb.w;
        SsF[lk+0][lr]=(float)(2*sa.x-1); SsF[lk+1][lr]=(float)(2*sa.y-1);
        SsF[lk+2][lr]=(float)(2*sa.z-1); SsF[lk+3][lr]=(float)(2*sa.w-1);
        SsF[lk+4][lr]=(float)(2*sb.x-1); SsF[lk+5][lr]=(float)(2*sb.y-1);
        SsF[lk+6][lr]=(float)(2*sb.z-1); SsF[lk+7][lr]=(float)(2*sb.w-1);
        __syncthreads();
        #pragma unroll
        for (int k = 0; k < BK; ++k) {
            float av[8], bv[8];
            #pragma unroll
            for (int i = 0; i < 8; ++i) av[i] = XsF[k][ty*8+i];
            #pragma unroll
            for (int j = 0; j < 8; ++j) bv[j] = SsF[k][tx*8+j];
            #pragma unroll
            for (int i = 0; i < 8; ++i)
                #pragma unroll
                for (int j = 0; j < 8; ++j) acc[i][j] = fmaf(av[i], bv[j], acc[i][j]);
        }
    }
    #pragma unroll
    for (int i = 0; i < 8; ++i)
        #pragma unroll
        for (int j = 0; j < 8; ++j) acc[i][j] = fmaxf(acc[i][j], 0.f);
    #pragma unroll
    for (int o = 0; o < OD; ++o) {
        float vv[8];
        #pragma unroll
        for (int j = 0; j < 8; ++j) vv[j] = Vl[o][tx*8+j];
        float p[8];
        #pragma unroll
        for (int i = 0; i < 8; ++i) {
            float s = 0.f;
            #pragma unroll
            for (int j = 0; j < 8; ++j) s = fmaf(acc[i][j], vv[j], s);
            p[i] = s;
        }
        #pragma unroll
        for (int m = 8; m >= 1; m >>= 1)
            #pragma unroll
            for (int i = 0; i < 8; ++i) p[i] += __shfl_xor(p[i], m, 16);
        if (tx == 0) {
            #pragma unroll
            for (int i = 0; i < 8; ++i)
                atomicAdd(&out[(size_t)(bm + ty*8 + i) * OD + o], p[i]);
        }
    }
}

// ================= launch ==================================================
extern "C" void kernel_launch(void* const* d_in, const int* in_sizes, int n_in,
                              void* d_out, int out_size, void* d_ws, size_t ws_size,
                              hipStream_t stream) {
    const float* x       = (const float*)d_in[0];
    const int*   tile1   = (const int*)  d_in[1];
    const float* alphas1 = (const float*)d_in[2];
    const int*   tile2   = (const int*)  d_in[3];
    const float* alphas2 = (const float*)d_in[4];
    float*       out     = (float*)d_out;

    const size_t OFF_XQ = 0;                                  // 7168*1024
    const size_t OFF_SQ = OFF_XQ + (size_t)7168 * 1024;       // + 1024*832
    const size_t OFF_F  = OFF_SQ + (size_t)RP * KP2;          // + 16*1024*2
    const size_t NEED   = OFF_F + (size_t)16 * RP * 2;        // ~8.2 MB

    if (ws_size < NEED) {
        hipMemsetAsync(out, 0, (size_t)out_size * sizeof(float), stream);
        dim3 grid(B_ / BM, RP / BN);
        fused_tilednn<<<grid, 256, 0, stream>>>(x, tile1, alphas1, tile2, alphas2, out);
        return;
    }

    signed char*    Xqf   = (signed char*)((char*)d_ws + OFF_XQ);
    signed char*    Sq    = (signed char*)((char*)d_ws + OFF_SQ);
    unsigned short* Vfrag = (unsigned short*)((char*)d_ws + OFF_F);

    prep<<<NB_XQ + NB_SQ + NB_F + NB_Z, 256, 0, stream>>>(
        x, tile1, tile2, alphas1, alphas2, Xqf, Sq, Vfrag, out);
    gemm1<<<512, 256, 0, stream>>>(Xqf, Sq, Vfrag, out);
}